// Round 1
// 242.151 us; speedup vs baseline: 1.0501x; 1.0501x over previous
//
#include <hip/hip_runtime.h>
#include <math.h>

#define DIM 16
#define HID 32

typedef float  f32x4  __attribute__((ext_vector_type(4)));
typedef short  bf16x8 __attribute__((ext_vector_type(8)));
typedef float  v2f    __attribute__((ext_vector_type(2)));

#define ROW_STRIDE_B 80                    // LDS row: 32 bf16 = 64B data + 16B pad (16B-aligned)
#define LDS_PER_WAVE (64 * ROW_STRIDE_B)   // 5120 B

__device__ inline unsigned short f2bf(float f) {
    union { float f; unsigned u; } v; v.f = f;
    unsigned r = v.u + 0x7fffu + ((v.u >> 16) & 1u);   // RNE
    return (unsigned short)(r >> 16);
}

// gfx950 packed f32->bf16 (RNE). No builtin exists; inline asm per guide T12.
__device__ inline unsigned cvt_pk_bf16(float lo, float hi) {
    unsigned r;
    asm("v_cvt_pk_bf16_f32 %0, %1, %2" : "=v"(r) : "v"(lo), "v"(hi));
    return r;
}

// Packed-pair GELU, exact erf via A&S 7.1.26 (|err|<1.5e-7).
// Sign-free form: gelu(h) = 0.5h + 0.5|h| * erf(|h|/sqrt2)   (erf is odd)
// e^{-z^2} with z^2 = h^2/2 folded to one v_exp: 2^(h^2 * -log2(e)/2)
__device__ inline v2f gelu2(v2f h) {
    v2f hh  = h * (v2f){0.5f, 0.5f};                                   // 0.5h
    v2f ahh = __builtin_elementwise_abs(hh);                           // 0.5|h|
    v2f az  = ahh * (v2f){1.41421356237309505f, 1.41421356237309505f}; // |z| = |h|/sqrt2
    v2f den = __builtin_elementwise_fma(az, (v2f){0.3275911f, 0.3275911f},
                                        (v2f){1.0f, 1.0f});
    v2f t   = (v2f){__builtin_amdgcn_rcpf(den.x), __builtin_amdgcn_rcpf(den.y)};
    v2f h2  = h * h;
    v2f ex  = h2 * (v2f){-0.721347520444482f, -0.721347520444482f};    // -z^2*log2(e)
    v2f e   = (v2f){__builtin_amdgcn_exp2f(ex.x), __builtin_amdgcn_exp2f(ex.y)};
    v2f p   = __builtin_elementwise_fma(t, (v2f){1.061405429f, 1.061405429f},
                                        (v2f){-1.453152027f, -1.453152027f});
    p = __builtin_elementwise_fma(t, p, (v2f){1.421413741f, 1.421413741f});
    p = __builtin_elementwise_fma(t, p, (v2f){-0.284496736f, -0.284496736f});
    p = __builtin_elementwise_fma(t, p, (v2f){0.254829592f, 0.254829592f});
    p = p * t;
    v2f erfa = __builtin_elementwise_fma(-p, e, (v2f){1.0f, 1.0f});    // erf(|z|)
    return __builtin_elementwise_fma(ahh, erfa, hh);
}

__global__ __launch_bounds__(256) void fused_ln_mlp_mfma(
    const float* __restrict__ x,
    const float* __restrict__ ln_w,
    const float* __restrict__ ln_b,
    const float* __restrict__ w1,   // [HID][DIM] row-major
    const float* __restrict__ b1,   // [HID]
    const float* __restrict__ w2,   // [DIM][HID] row-major
    const float* __restrict__ b2,   // [DIM]
    float* __restrict__ out,
    int nrows)
{
    __shared__ __align__(16) unsigned char lds_all[4 * LDS_PER_WAVE];  // 20 KiB / block

    const int tid  = threadIdx.x;
    const int lane = tid & 63;
    const int wave = tid >> 6;
    const int q    = lane >> 4;     // quad index 0..3
    const int c    = lane & 15;     // within-16 index

    unsigned char* nbuf = lds_all + wave * LDS_PER_WAVE;   // per-wave private slice
    const int rowbase = (blockIdx.x * 4 + wave) * 64;      // 64 rows per wave
    (void)nrows;

    // ---- per-lane weight fragments (loaded once, L2/L3-cached) ----
    // OPERAND-SWAPPED matmuls: we compute H^T = W1 * Xn^T and Y^T = W2 * P^T.
    // A/B fragment layouts are symmetric (A[row=c][k=8q+j], B[k=8q+j][col=c]),
    // so these are byte-identical to the old B-operand fragments — only the
    // mfma() argument order changes. Payoff: C-layout lands 4 CONSECUTIVE
    // features (hid / dim 4q..4q+3) of one row in each lane.
    // W1 as A-operand: A[row=c (hid within half t)][k=8q+j (dim, 0-pad k>=16)]
    bf16x8 aW1[2];
    #pragma unroll
    for (int t = 0; t < 2; t++) {
        bf16x8 f = {0, 0, 0, 0, 0, 0, 0, 0};
        if (q < 2) {
            const float* wp = w1 + (c + 16 * t) * DIM + q * 8;
            #pragma unroll
            for (int j = 0; j < 8; j++)
                ((unsigned short*)&f)[j] = f2bf(wp[j]);
        }
        aW1[t] = f;
    }
    // W2 as A-operand: A[row=c (dim)][k=8q+j (hid)] = w2[c*HID + 8q+j]
    bf16x8 aW2;
    {
        const float* wp = w2 + c * HID + q * 8;
        #pragma unroll
        for (int j = 0; j < 8; j++)
            ((unsigned short*)&aW2)[j] = f2bf(wp[j]);
    }
    // biases along the per-lane feature quad 4q..4q+3
    const f32x4 b1v0 = *(const f32x4*)(b1 + 4 * q);        // hid 4q+r   (t=0)
    const f32x4 b1v1 = *(const f32x4*)(b1 + 16 + 4 * q);   // hid 16+4q+r (t=1)
    const f32x4 b2v4 = *(const f32x4*)(b2 + 4 * q);        // dim 4q+r

    // ---- phase 1: lane=row load + LayerNorm (fp32, packed v2f) ----
    const float* xr = x + (size_t)(rowbase + lane) * DIM;
    v2f xv2[8];
    {
        f32x4 t0 = *(const f32x4*)(xr + 0);
        f32x4 t1 = *(const f32x4*)(xr + 4);
        f32x4 t2 = *(const f32x4*)(xr + 8);
        f32x4 t3 = *(const f32x4*)(xr + 12);
        xv2[0] = (v2f){t0.x, t0.y}; xv2[1] = (v2f){t0.z, t0.w};
        xv2[2] = (v2f){t1.x, t1.y}; xv2[3] = (v2f){t1.z, t1.w};
        xv2[4] = (v2f){t2.x, t2.y}; xv2[5] = (v2f){t2.z, t2.w};
        xv2[6] = (v2f){t3.x, t3.y}; xv2[7] = (v2f){t3.z, t3.w};
    }
    v2f s = xv2[0] + xv2[1];
    s += xv2[2] + xv2[3];
    s += xv2[4] + xv2[5];
    s += xv2[6] + xv2[7];
    float mu = (s.x + s.y) * (1.0f / DIM);
    v2f mu2 = (v2f){mu, mu};
    v2f vs = (v2f){0.0f, 0.0f};
    #pragma unroll
    for (int i = 0; i < 8; i++) {
        v2f d = xv2[i] - mu2;
        vs = __builtin_elementwise_fma(d, d, vs);
    }
    float var = (vs.x + vs.y) * (1.0f / DIM);
    float a = __builtin_amdgcn_rsqf(var + 1e-5f);
    float cc = -mu * a;

    const v2f* lnw2 = (const v2f*)ln_w;
    const v2f* lnb2 = (const v2f*)ln_b;
    v2f a2 = (v2f){a, a};
    v2f c2 = (v2f){cc, cc};
    unsigned dw[8];
    #pragma unroll
    for (int i = 0; i < 8; i++) {
        v2f xh = __builtin_elementwise_fma(xv2[i], a2, c2);
        v2f r  = __builtin_elementwise_fma(xh, lnw2[i], lnb2[i]);
        dw[i] = cvt_pk_bf16(r.x, r.y);         // dims 2i (lo), 2i+1 (hi)
    }

    // write xn row as 32 bf16 (upper 16 = K-padding zeros)
    {
        int4 w0, w1v, zz;
        w0.x  = (int)dw[0]; w0.y  = (int)dw[1]; w0.z  = (int)dw[2]; w0.w  = (int)dw[3];
        w1v.x = (int)dw[4]; w1v.y = (int)dw[5]; w1v.z = (int)dw[6]; w1v.w = (int)dw[7];
        zz.x = zz.y = zz.z = zz.w = 0;
        int4* rowp = (int4*)(nbuf + lane * ROW_STRIDE_B);
        rowp[0] = w0; rowp[1] = w1v; rowp[2] = zz; rowp[3] = zz;
    }
    asm volatile("s_waitcnt lgkmcnt(0)" ::: "memory");   // wave-lockstep: writes visible

    // ---- W1 matmul (swapped) + bias + packed GELU + P writeback, per rc ----
    // H^T tile: accH[t][r] = H[rc*16+c][hid 16t+4q+r]
    // P-write per (rc,t): one ds_write_b64 (4 consecutive hids as bf16).
    // Safe vs the xfrag read: P-write data depends on xfrag via mfma, and
    // same-wave DS ops complete in order; iteration rc only touches its own
    // 16 LDS rows.
    #pragma unroll
    for (int rc = 0; rc < 4; rc++) {
        const bf16x8 xfrag =
            *(const bf16x8*)(nbuf + (rc * 16 + c) * ROW_STRIDE_B + q * 16);
        f32x4 z = {0.f, 0.f, 0.f, 0.f};
        f32x4 h0 = __builtin_amdgcn_mfma_f32_16x16x32_bf16(aW1[0], xfrag, z, 0, 0, 0);
        f32x4 h1 = __builtin_amdgcn_mfma_f32_16x16x32_bf16(aW1[1], xfrag, z, 0, 0, 0);
        h0 += b1v0;
        h1 += b1v1;
        v2f g0 = gelu2((v2f){h0.x, h0.y});    // hid 4q+0, 4q+1
        v2f g1 = gelu2((v2f){h0.z, h0.w});    // hid 4q+2, 4q+3
        v2f g2 = gelu2((v2f){h1.x, h1.y});    // hid 16+4q+0, 16+4q+1
        v2f g3 = gelu2((v2f){h1.z, h1.w});    // hid 16+4q+2, 16+4q+3
        unsigned d0 = cvt_pk_bf16(g0.x, g0.y);
        unsigned d1 = cvt_pk_bf16(g1.x, g1.y);
        unsigned d2 = cvt_pk_bf16(g2.x, g2.y);
        unsigned d3 = cvt_pk_bf16(g3.x, g3.y);
        unsigned char* prow = nbuf + (rc * 16 + c) * ROW_STRIDE_B;
        int2 lo; lo.x = (int)d0; lo.y = (int)d1;
        int2 hi; hi.x = (int)d2; hi.y = (int)d3;
        *(int2*)(prow + 8 * q)      = lo;     // hids 4q..4q+3       (bytes 8q..8q+8)
        *(int2*)(prow + 32 + 8 * q) = hi;     // hids 16+4q..16+4q+3
    }
    asm volatile("s_waitcnt lgkmcnt(0)" ::: "memory");   // P writes visible

    // ---- W2 matmul (swapped) + epilogue: Y^T gives lane a contiguous float4
    // of the output row -> fully-coalesced dwordx4 loads/stores.
    #pragma unroll
    for (int rc = 0; rc < 4; rc++) {
        const bf16x8 pfrag =
            *(const bf16x8*)(nbuf + (rc * 16 + c) * ROW_STRIDE_B + q * 16);
        f32x4 z = {0.f, 0.f, 0.f, 0.f};
        f32x4 y = __builtin_amdgcn_mfma_f32_16x16x32_bf16(aW2, pfrag, z, 0, 0, 0);
        // y[r] = Y[rowbase + rc*16 + c][dim 4q+r]
        size_t base = (size_t)(rowbase + rc * 16 + c) * DIM + 4 * q;
        f32x4 xres = *(const f32x4*)(x + base);          // L1/L2-hot re-read
        f32x4 o = y + b2v4 + xres;
        __builtin_nontemporal_store(o, (f32x4*)(out + base));  // don't evict x from L3
    }
}

extern "C" void kernel_launch(void* const* d_in, const int* in_sizes, int n_in,
                              void* d_out, int out_size, void* d_ws, size_t ws_size,
                              hipStream_t stream) {
    const float* x    = (const float*)d_in[0];
    const float* ln_w = (const float*)d_in[1];
    const float* ln_b = (const float*)d_in[2];
    const float* w1   = (const float*)d_in[3];
    const float* b1   = (const float*)d_in[4];
    const float* w2   = (const float*)d_in[5];
    const float* b2   = (const float*)d_in[6];
    float* out = (float*)d_out;

    int nrows = in_sizes[0] / DIM;            // 2,097,152
    int rows_per_block = 256;                 // 4 waves x 64 rows
    int grid = (nrows + rows_per_block - 1) / rows_per_block;

    fused_ln_mlp_mfma<<<grid, 256, 0, stream>>>(
        x, ln_w, ln_b, w1, b1, w2, b2, out, nrows);
}

// Round 3
// 234.712 us; speedup vs baseline: 1.0834x; 1.0317x over previous
//
#include <hip/hip_runtime.h>
#include <math.h>

#define DIM 16
#define HID 32

typedef float  f32x4  __attribute__((ext_vector_type(4)));
typedef float  v2f    __attribute__((ext_vector_type(2)));
typedef short  bf16x8 __attribute__((ext_vector_type(8)));

__device__ inline unsigned short f2bf(float f) {
    union { float f; unsigned u; } v; v.f = f;
    unsigned r = v.u + 0x7fffu + ((v.u >> 16) & 1u);   // RNE
    return (unsigned short)(r >> 16);
}

// gfx950 packed f32->bf16 (RNE); no builtin exists, inline asm per guide T12.
__device__ inline unsigned cvt_pk_bf16(float lo, float hi) {
    unsigned r;
    asm("v_cvt_pk_bf16_f32 %0, %1, %2" : "=v"(r) : "v"(lo), "v"(hi));
    return r;
}

// Packed-pair GELU, exact erf via A&S 7.1.26 (|err|<1.5e-7), sign-free:
// gelu(h) = 0.5h + 0.5|h| * erf(|h|/sqrt2);  e^{-z^2} via one v_exp2 each.
__device__ inline v2f gelu2(v2f h) {
    v2f hh  = h * (v2f){0.5f, 0.5f};                                   // 0.5h
    v2f ahh = __builtin_elementwise_abs(hh);                           // 0.5|h|
    v2f az  = ahh * (v2f){1.41421356237309505f, 1.41421356237309505f}; // |z|
    v2f den = __builtin_elementwise_fma(az, (v2f){0.3275911f, 0.3275911f},
                                        (v2f){1.0f, 1.0f});
    v2f t   = (v2f){__builtin_amdgcn_rcpf(den.x), __builtin_amdgcn_rcpf(den.y)};
    v2f h2  = h * h;
    v2f ex  = h2 * (v2f){-0.721347520444482f, -0.721347520444482f};    // -z^2*log2e
    v2f e   = (v2f){__builtin_amdgcn_exp2f(ex.x), __builtin_amdgcn_exp2f(ex.y)};
    v2f p   = __builtin_elementwise_fma(t, (v2f){1.061405429f, 1.061405429f},
                                        (v2f){-1.453152027f, -1.453152027f});
    p = __builtin_elementwise_fma(t, p, (v2f){1.421413741f, 1.421413741f});
    p = __builtin_elementwise_fma(t, p, (v2f){-0.284496736f, -0.284496736f});
    p = __builtin_elementwise_fma(t, p, (v2f){0.254829592f, 0.254829592f});
    p = p * t;
    v2f erfa = __builtin_elementwise_fma(-p, e, (v2f){1.0f, 1.0f});    // erf(|z|)
    return __builtin_elementwise_fma(ahh, erfa, hh);
}

// Fully-in-register pipeline using ONLY the verified K=32 MFMA.
// Wave owns 64 rows as 4 tiles of 16. Lane (q = lane>>4, c = lane&15) owns
// dims/hids 4q..4q+3 of row rc*16+c in every stage; B-fragment k-slots
// 8q..8q+7 are fed by a CHOSEN K-permutation so the data is lane-local:
//   W1: dim 4q+j -> k=8q+j (j<4), k=8q+4..8q+7 zero-padded.
//   W2: hid(k=8q+j) = j<4 ? 4q+j : 16+4q+(j-4)   (bijection, no padding,
//       exactly the 8 GELU outputs this lane computed) -> ONE K=32 MFMA.
// A-fragments (weights) are per-lane global gathers with the same
// permutation, loaded once. D layout (col=c, row=4q+r) == residual ==
// store layout. No LDS, no barriers, x read once.
__global__ __launch_bounds__(256) void fused_ln_mlp_mfma(
    const float* __restrict__ x,
    const float* __restrict__ ln_w,
    const float* __restrict__ ln_b,
    const float* __restrict__ w1,   // [HID][DIM] row-major
    const float* __restrict__ b1,   // [HID]
    const float* __restrict__ w2,   // [DIM][HID] row-major
    const float* __restrict__ b2,   // [DIM]
    float* __restrict__ out,
    int nrows)
{
    const int tid  = threadIdx.x;
    const int lane = tid & 63;
    const int wave = tid >> 6;
    const int q    = lane >> 4;     // quad index 0..3
    const int c    = lane & 15;     // within-16 index
    const int rowbase = (blockIdx.x * 4 + wave) * 64;
    (void)nrows;

    // ---- per-lane weight fragments (loaded once; L2/L3-hot across blocks) ----
    // W1 A-frag, hid-half t: A[row = hid 16t+c][k=8q+j] = w1[(16t+c)*DIM + 4q+j]
    // for j<4, zero for j>=4 (k-permuted zero padding).
    bf16x8 aW1[2];
    #pragma unroll
    for (int t = 0; t < 2; t++) {
        bf16x8 f = {0, 0, 0, 0, 0, 0, 0, 0};
        const float* wp = w1 + (16 * t + c) * DIM + 4 * q;
        #pragma unroll
        for (int j = 0; j < 4; j++)
            ((unsigned short*)&f)[j] = f2bf(wp[j]);
        aW1[t] = f;
    }
    // W2 A-frag: A[row = dim c][k=8q+j] = w2[c*HID + hid(q,j)],
    // hid(q,j) = j<4 ? 4q+j : 16+4q+(j-4).
    bf16x8 aW2;
    {
        const float* wp = w2 + c * HID;
        #pragma unroll
        for (int j = 0; j < 8; j++) {
            int hid = (j < 4) ? (4 * q + j) : (16 + 4 * q + (j - 4));
            ((unsigned short*)&aW2)[j] = f2bf(wp[hid]);
        }
    }
    const f32x4 b1q0 = *(const f32x4*)(b1 + 4 * q);        // hid 4q+r
    const f32x4 b1q1 = *(const f32x4*)(b1 + 16 + 4 * q);   // hid 16+4q+r
    const f32x4 b2q  = *(const f32x4*)(b2 + 4 * q);        // dim 4q+r
    const f32x4 lnw4 = *(const f32x4*)(ln_w + 4 * q);
    const f32x4 lnb4 = *(const f32x4*)(ln_b + 4 * q);

    // ---- x loads: fragment layout == residual layout (dims 4q..4q+3) ----
    // Per tile the wave touches a dense 1 KiB region (16 rows x 64 B).
    f32x4 xv[4];
    #pragma unroll
    for (int rc = 0; rc < 4; rc++)
        xv[rc] = *(const f32x4*)(x + (size_t)(rowbase + rc * 16 + c) * DIM + 4 * q);

    #pragma unroll
    for (int rc = 0; rc < 4; rc++) {
        const f32x4 v = xv[rc];

        // LN stats: lane-local (s, ss), then 4-lane butterfly over the q bits.
        float s  = (v.x + v.y) + (v.z + v.w);
        float ss = fmaf(v.x, v.x, fmaf(v.y, v.y, fmaf(v.z, v.z, v.w * v.w)));
        s  += __shfl_xor(s, 16);  ss += __shfl_xor(ss, 16);
        s  += __shfl_xor(s, 32);  ss += __shfl_xor(ss, 32);
        float mu  = s * (1.0f / DIM);
        float var = fmaf(-mu, mu, ss * (1.0f / DIM));
        float a   = __builtin_amdgcn_rsqf(var + 1e-5f);

        f32x4 aw  = lnw4 * a;
        f32x4 muv = {mu, mu, mu, mu};
        f32x4 off = __builtin_elementwise_fma(-muv, aw, lnb4);
        f32x4 xn  = __builtin_elementwise_fma(v, aw, off);

        // B-frag for W1: k=8q..8q+3 = dims 4q..4q+3, k=8q+4..8q+7 = 0.
        union { unsigned u[4]; bf16x8 f; } bX;
        bX.u[0] = cvt_pk_bf16(xn.x, xn.y);
        bX.u[1] = cvt_pk_bf16(xn.z, xn.w);
        bX.u[2] = 0u;
        bX.u[3] = 0u;

        // ---- W1 (Hᵀ = W1 · Xnᵀ), two hid halves, verified K=32 MFMA ----
        const f32x4 z = {0.f, 0.f, 0.f, 0.f};
        f32x4 h0 = __builtin_amdgcn_mfma_f32_16x16x32_bf16(aW1[0], bX.f, z, 0, 0, 0) + b1q0;
        f32x4 h1 = __builtin_amdgcn_mfma_f32_16x16x32_bf16(aW1[1], bX.f, z, 0, 0, 0) + b1q1;

        // ---- packed GELU -> B-frag for W2 (k-permuted, lane-local) ----
        v2f g0 = gelu2((v2f){h0.x, h0.y});    // hid 4q+0, 4q+1      -> k 8q+0,1
        v2f g1 = gelu2((v2f){h0.z, h0.w});    // hid 4q+2, 4q+3      -> k 8q+2,3
        v2f g2 = gelu2((v2f){h1.x, h1.y});    // hid 16+4q+0, +1     -> k 8q+4,5
        v2f g3 = gelu2((v2f){h1.z, h1.w});    // hid 16+4q+2, +3     -> k 8q+6,7
        union { unsigned u[4]; bf16x8 f; } bP;
        bP.u[0] = cvt_pk_bf16(g0.x, g0.y);
        bP.u[1] = cvt_pk_bf16(g1.x, g1.y);
        bP.u[2] = cvt_pk_bf16(g2.x, g2.y);
        bP.u[3] = cvt_pk_bf16(g3.x, g3.y);

        // ---- W2 (Yᵀ = W2 · Pᵀ): ONE K=32 MFMA covers all 32 hids ----
        f32x4 acc = __builtin_amdgcn_mfma_f32_16x16x32_bf16(aW2, bP.f, z, 0, 0, 0);

        // ---- epilogue: + b2 + residual, coalesced nt dwordx4 store ----
        f32x4 o = acc + b2q + v;
        size_t base = (size_t)(rowbase + rc * 16 + c) * DIM + 4 * q;
        __builtin_nontemporal_store(o, (f32x4*)(out + base));
    }
}

extern "C" void kernel_launch(void* const* d_in, const int* in_sizes, int n_in,
                              void* d_out, int out_size, void* d_ws, size_t ws_size,
                              hipStream_t stream) {
    const float* x    = (const float*)d_in[0];
    const float* ln_w = (const float*)d_in[1];
    const float* ln_b = (const float*)d_in[2];
    const float* w1   = (const float*)d_in[3];
    const float* b1   = (const float*)d_in[4];
    const float* w2   = (const float*)d_in[5];
    const float* b2   = (const float*)d_in[6];
    float* out = (float*)d_out;

    int nrows = in_sizes[0] / DIM;            // 2,097,152
    int rows_per_block = 256;                 // 4 waves x 64 rows
    int grid = (nrows + rows_per_block - 1) / rows_per_block;

    fused_ln_mlp_mfma<<<grid, 256, 0, stream>>>(
        x, ln_w, ln_b, w1, b1, w2, b2, out, nrows);
}